// Round 6
// baseline (399.676 us; speedup 1.0000x reference)
//
#include <hip/hip_runtime.h>
#include <hip/hip_bf16.h>
#include <math.h>

#define KNN 5
#define K3 27
#define CENTER 13
#define NCLASSES 21
#define DIM_D 32
#define DIM_H 128
#define DIM_W 2048

// full sort key (16 bits, z-major): z<<11 | y<<4 | x>>7
// LSD radix: digit0 = key & 0xFF (y-low:4, x>>7:4), digit1 = key >> 8 (z:5, y-high:3)
// payload w.y = x | y<<11 | z<<18 -> d0 = (w.y>>7)&0xFF, d1 = (w.y>>15)&0xFF
#define RADIX 256
#define BIN_PTS 2048
#define BIN_THREADS 256

__device__ __forceinline__ unsigned key16(int x, int y, int z) {
    return ((unsigned)z << 11) | ((unsigned)y << 4) | ((unsigned)x >> 7);
}

// ---------------- pass 0: global digit-0 histogram ----------------
__global__ __launch_bounds__(256) void hist0_kernel(
    const int* __restrict__ px, const int* __restrict__ py,
    unsigned* __restrict__ h0, int P)
{
    __shared__ unsigned lh0[RADIX];
    int t = threadIdx.x;
    lh0[t] = 0;
    __syncthreads();
    int base4 = blockIdx.x * 1024 + t;
#pragma unroll
    for (int g = 0; g < 4; ++g) {
        int i4 = base4 + g * 256;
        int i0 = i4 * 4;
        if (i0 + 3 < P) {
            int4 X = ((const int4*)px)[i4];
            int4 Y = ((const int4*)py)[i4];
            atomicAdd(&lh0[(((unsigned)Y.x & 0xF) << 4) | ((unsigned)X.x >> 7)], 1u);
            atomicAdd(&lh0[(((unsigned)Y.y & 0xF) << 4) | ((unsigned)X.y >> 7)], 1u);
            atomicAdd(&lh0[(((unsigned)Y.z & 0xF) << 4) | ((unsigned)X.z >> 7)], 1u);
            atomicAdd(&lh0[(((unsigned)Y.w & 0xF) << 4) | ((unsigned)X.w >> 7)], 1u);
        } else {
            for (int i = i0; i < P; ++i)
                atomicAdd(&lh0[(((unsigned)py[i] & 0xF) << 4) | ((unsigned)px[i] >> 7)], 1u);
        }
    }
    __syncthreads();
    if (lh0[t]) atomicAdd(&h0[t], lh0[t]);
}

// exclusive scan of one 256-entry histogram in place
__global__ __launch_bounds__(256) void scan256_kernel(unsigned* __restrict__ h)
{
    __shared__ unsigned ws[4];
    int t = threadIdx.x, lane = t & 63, wid = t >> 6;
    unsigned a = h[t], ia = a;
#pragma unroll
    for (int off = 1; off < 64; off <<= 1) {
        unsigned v = __shfl_up(ia, off);
        if (lane >= off) ia += v;
    }
    if (lane == 63) ws[wid] = ia;
    __syncthreads();
    unsigned b = 0;
#pragma unroll
    for (int w = 0; w < 4; ++w) b += (w < wid) ? ws[w] : 0u;
    h[t] = b + ia - a;
}

// ---------------- binning machinery ----------------
struct BinShared {
    unsigned lh[RADIX];
    unsigned lscan[RADIX];
    unsigned gbase[RADIX];
    unsigned wsum[4];
    uint4 stage[BIN_PTS];   // 32 KB
};

__device__ __forceinline__ void bin_local_scan(BinShared& S, int t)
{
    int lane = t & 63, wid = t >> 6;
    unsigned c = S.lh[t];
    unsigned inc = c;
#pragma unroll
    for (int off = 1; off < 64; off <<= 1) {
        unsigned v = __shfl_up(inc, off);
        if (lane >= off) inc += v;
    }
    if (lane == 63) S.wsum[wid] = inc;
    __syncthreads();
    unsigned wb = 0;
#pragma unroll
    for (int w = 0; w < 4; ++w) wb += (w < wid) ? S.wsum[w] : 0u;
    S.lscan[t] = wb + inc - c;
}

// pass 1: read original SoA arrays, bin by digit0 (cursor atomics on h0;
// grouping by d0 is exact, intra-d0 order is don't-care)
__global__ __launch_bounds__(BIN_THREADS) void bin_pass1_kernel(
    const float* __restrict__ ur, const int* __restrict__ px,
    const int* __restrict__ py, const int* __restrict__ pz,
    unsigned* __restrict__ g0, uint4* __restrict__ outp, int P)
{
    __shared__ BinShared S;
    int t = threadIdx.x;
    int bstart = blockIdx.x * BIN_PTS;
    int n = min(BIN_PTS, P - bstart);
    S.lh[t] = 0;
    __syncthreads();

    uint4 pay[8];
    unsigned rk[8], dg[8];
#pragma unroll
    for (int g = 0; g < 2; ++g) {
        int i4 = (bstart >> 2) + g * 256 + t;
        int i0 = i4 * 4;
        if (i0 + 3 < P) {
            int4 X = ((const int4*)px)[i4];
            int4 Y = ((const int4*)py)[i4];
            int4 Z = ((const int4*)pz)[i4];
            float4 U = ((const float4*)ur)[i4];
            int xs[4] = {X.x, X.y, X.z, X.w};
            int ys[4] = {Y.x, Y.y, Y.z, Y.w};
            int zs[4] = {Z.x, Z.y, Z.z, Z.w};
            float us[4] = {U.x, U.y, U.z, U.w};
#pragma unroll
            for (int c = 0; c < 4; ++c) {
                int j = g * 4 + c;
                unsigned k = key16(xs[c], ys[c], zs[c]);
                dg[j] = k & 0xFFu;
                rk[j] = atomicAdd(&S.lh[dg[j]], 1u);
                pay[j] = make_uint4(__float_as_uint(us[c]),
                    (unsigned)xs[c] | ((unsigned)ys[c] << 11) | ((unsigned)zs[c] << 18),
                    (unsigned)(i0 + c), 0u);
            }
        } else {
#pragma unroll
            for (int c = 0; c < 4; ++c) {
                int j = g * 4 + c;
                int gi = i0 + c;
                if (gi < P) {
                    int x = px[gi], y = py[gi], z = pz[gi];
                    unsigned k = key16(x, y, z);
                    dg[j] = k & 0xFFu;
                    rk[j] = atomicAdd(&S.lh[dg[j]], 1u);
                    pay[j] = make_uint4(__float_as_uint(ur[gi]),
                        (unsigned)x | ((unsigned)y << 11) | ((unsigned)z << 18),
                        (unsigned)gi, 0u);
                } else {
                    dg[j] = 0xFFFFFFFFu;
                }
            }
        }
    }
    __syncthreads();
    bin_local_scan(S, t);
    S.gbase[t] = S.lh[t] ? atomicAdd(&g0[t], S.lh[t]) : 0u;
    __syncthreads();
#pragma unroll
    for (int j = 0; j < 8; ++j)
        if (dg[j] != 0xFFFFFFFFu)
            S.stage[S.lscan[dg[j]] + rk[j]] = pay[j];
    __syncthreads();
#pragma unroll
    for (int j = 0; j < 8; ++j) {
        int s = j * 256 + t;
        if (s < n) {
            uint4 v = S.stage[s];
            unsigned d = (v.y >> 7) & 0xFFu;
            unsigned pos = S.gbase[d] + ((unsigned)s - S.lscan[d]);
            outp[pos] = v;
        }
    }
}

// per-pass-2-block digit-1 histogram -> M[d1 * gridB + block] (digit-major)
__global__ __launch_bounds__(BIN_THREADS) void hist_p2_kernel(
    const uint4* __restrict__ inp, unsigned* __restrict__ M,
    int gridB, int P)
{
    __shared__ unsigned lh[RADIX];
    int t = threadIdx.x;
    lh[t] = 0;
    __syncthreads();
    int bstart = blockIdx.x * BIN_PTS;
#pragma unroll
    for (int j = 0; j < 8; ++j) {
        int i = bstart + j * 256 + t;
        if (i < P) {
            uint4 v = inp[i];
            atomicAdd(&lh[(v.y >> 15) & 0xFFu], 1u);
        }
    }
    __syncthreads();
    M[(unsigned)t * (unsigned)gridB + blockIdx.x] = lh[t];
}

// flat exclusive scan over N = 256*gridB entries (single block, 1024 thr)
__global__ __launch_bounds__(1024) void scan_mat_kernel(
    unsigned* __restrict__ M, int N)
{
    __shared__ unsigned wsum[16];
    int t = threadIdx.x, lane = t & 63, wid = t >> 6;
    int C = (N + 1023) / 1024;
    int lo = t * C, hi = min(lo + C, N);

    unsigned s = 0;
    for (int i = lo; i < hi; ++i) s += M[i];
    unsigned incl = s;
#pragma unroll
    for (int off = 1; off < 64; off <<= 1) {
        unsigned v = __shfl_up(incl, off);
        if (lane >= off) incl += v;
    }
    if (lane == 63) wsum[wid] = incl;
    __syncthreads();
    if (wid == 0 && lane < 16) {
        unsigned v = wsum[lane], iv = v;
#pragma unroll
        for (int off = 1; off < 16; off <<= 1) {
            unsigned u = __shfl_up(iv, off);
            if (lane >= off) iv += u;
        }
        wsum[lane] = iv - v;
    }
    __syncthreads();
    unsigned run = wsum[wid] + (incl - s);
    for (int i = lo; i < hi; ++i) {
        unsigned v = M[i];
        M[i] = run;
        run += v;
    }
}

// pass 2 STABLE: deterministic per-(digit,block) base from scanned M.
// No reservation atomics -> block chunks land in block order -> exact
// full-key grouping (restores R2's wave-level neighborhood locality).
__global__ __launch_bounds__(BIN_THREADS) void bin_pass2_stable_kernel(
    const uint4* __restrict__ inp, const unsigned* __restrict__ M,
    uint4* __restrict__ outp, int gridB, int P)
{
    __shared__ BinShared S;
    int t = threadIdx.x;
    int bstart = blockIdx.x * BIN_PTS;
    int n = min(BIN_PTS, P - bstart);
    S.lh[t] = 0;
    __syncthreads();

    uint4 pay[8];
    unsigned rk[8], dg[8];
#pragma unroll
    for (int j = 0; j < 8; ++j) {
        int i = bstart + j * 256 + t;
        if (i < P) {
            uint4 v = inp[i];
            pay[j] = v;
            dg[j] = (v.y >> 15) & 0xFFu;
            rk[j] = atomicAdd(&S.lh[dg[j]], 1u);
        } else {
            dg[j] = 0xFFFFFFFFu;
        }
    }
    __syncthreads();
    bin_local_scan(S, t);
    S.gbase[t] = M[(unsigned)t * (unsigned)gridB + blockIdx.x];
    __syncthreads();
#pragma unroll
    for (int j = 0; j < 8; ++j)
        if (dg[j] != 0xFFFFFFFFu)
            S.stage[S.lscan[dg[j]] + rk[j]] = pay[j];
    __syncthreads();
#pragma unroll
    for (int j = 0; j < 8; ++j) {
        int s = j * 256 + t;
        if (s < n) {
            uint4 v = S.stage[s];
            unsigned d = (v.y >> 15) & 0xFFu;
            unsigned pos = S.gbase[d] + ((unsigned)s - S.lscan[d]);
            outp[pos] = v;
        }
    }
}

// pass 2 fallback (R4): atomic chunk reservation (nondeterministic order)
__global__ __launch_bounds__(BIN_THREADS) void bin_pass2_kernel(
    const uint4* __restrict__ inp, unsigned* __restrict__ g1,
    uint4* __restrict__ outp, int P)
{
    __shared__ BinShared S;
    int t = threadIdx.x;
    int bstart = blockIdx.x * BIN_PTS;
    int n = min(BIN_PTS, P - bstart);
    S.lh[t] = 0;
    __syncthreads();

    uint4 pay[8];
    unsigned rk[8], dg[8];
#pragma unroll
    for (int j = 0; j < 8; ++j) {
        int i = bstart + j * 256 + t;
        if (i < P) {
            uint4 v = inp[i];
            pay[j] = v;
            dg[j] = (v.y >> 15) & 0xFFu;
            rk[j] = atomicAdd(&S.lh[dg[j]], 1u);
        } else {
            dg[j] = 0xFFFFFFFFu;
        }
    }
    __syncthreads();
    bin_local_scan(S, t);
    S.gbase[t] = S.lh[t] ? atomicAdd(&g1[t], S.lh[t]) : 0u;
    __syncthreads();
#pragma unroll
    for (int j = 0; j < 8; ++j)
        if (dg[j] != 0xFFFFFFFFu)
            S.stage[S.lscan[dg[j]] + rk[j]] = pay[j];
    __syncthreads();
#pragma unroll
    for (int j = 0; j < 8; ++j) {
        int s = j * 256 + t;
        if (s < n) {
            uint4 v = S.stage[s];
            unsigned d = (v.y >> 15) & 0xFFu;
            unsigned pos = S.gbase[d] + ((unsigned)s - S.lscan[d]);
            outp[pos] = v;
        }
    }
}

// global d1 histogram for the fallback path
__global__ __launch_bounds__(256) void hist1_kernel(
    const int* __restrict__ py, const int* __restrict__ pz,
    unsigned* __restrict__ h1, int P)
{
    __shared__ unsigned lh1[RADIX];
    int t = threadIdx.x;
    lh1[t] = 0;
    __syncthreads();
    int base4 = blockIdx.x * 1024 + t;
#pragma unroll
    for (int g = 0; g < 4; ++g) {
        int i4 = base4 + g * 256;
        int i0 = i4 * 4;
        if (i0 + 3 < P) {
            int4 Y = ((const int4*)py)[i4];
            int4 Z = ((const int4*)pz)[i4];
            atomicAdd(&lh1[((unsigned)Z.x << 3) | ((unsigned)Y.x >> 4)], 1u);
            atomicAdd(&lh1[((unsigned)Z.y << 3) | ((unsigned)Y.y >> 4)], 1u);
            atomicAdd(&lh1[((unsigned)Z.z << 3) | ((unsigned)Y.z >> 4)], 1u);
            atomicAdd(&lh1[((unsigned)Z.w << 3) | ((unsigned)Y.w >> 4)], 1u);
        } else {
            for (int i = i0; i < P; ++i)
                atomicAdd(&lh1[((unsigned)pz[i] << 3) | ((unsigned)py[i] >> 4)], 1u);
        }
    }
    __syncthreads();
    if (lh1[t]) atomicAdd(&h1[t], lh1[t]);
}

// ---------------- KNN main kernel (R1-verified body) ----------------
__device__ __forceinline__ void bev_knn_body(
    const float* __restrict__ pr, const int* __restrict__ pa,
    float u, int x, int y, int z, int oidx, int* __restrict__ out)
{
    float dist[K3];
#pragma unroll
    for (int k = 0; k < K3; ++k) {
        const int dz = k / 9 - 1;
        const int dy = (k / 3) % 3 - 1;
        const int dx = k % 3 - 1;
        int zz = z + dz, yy = y + dy, xx = x + dx;
        bool ok = ((unsigned)zz < (unsigned)DIM_D) &
                  ((unsigned)yy < (unsigned)DIM_H) &
                  ((unsigned)xx < (unsigned)DIM_W);
        int zi = ok ? zz : 0;
        int yi = ok ? yy : 0;
        int xi = ok ? xx : 0;
        float r = pr[((size_t)zi * DIM_H + yi) * DIM_W + xi];
        r = ok ? r : 0.0f;
        r = (r < 0.0f) ? INFINITY : r;
        float d = fabsf(r - u);
        dist[k] = (k == CENTER) ? 0.0f : d;
    }

    float bd[KNN];
    int   bk[KNN];
#pragma unroll
    for (int j = 0; j < KNN; ++j) { bd[j] = INFINITY; bk[j] = -1; }
#pragma unroll
    for (int k = 0; k < K3; ++k) {
        float dcur = dist[k];
        int   kcur = k;
#pragma unroll
        for (int j = 0; j < KNN; ++j) {
            bool take = dcur < bd[j];
            float td = bd[j]; int tk = bk[j];
            bd[j] = take ? dcur : bd[j];
            bk[j] = take ? kcur : bk[j];
            dcur  = take ? td : dcur;
            kcur  = take ? tk : kcur;
        }
    }

    int votes[KNN];
#pragma unroll
    for (int j = 0; j < KNN; ++j) {
        int k = bk[j];
        const int dz = k / 9 - 1;
        const int dy = (k / 3) % 3 - 1;
        const int dx = k % 3 - 1;
        int zz = z + dz, yy = y + dy, xx = x + dx;
        bool ok = ((unsigned)zz < (unsigned)DIM_D) &
                  ((unsigned)yy < (unsigned)DIM_H) &
                  ((unsigned)xx < (unsigned)DIM_W);
        int zi = ok ? zz : 0;
        int yi = ok ? yy : 0;
        int xi = ok ? xx : 0;
        int cls = pa[((size_t)zi * DIM_H + yi) * DIM_W + xi];
        cls = ok ? cls : 0;
        cls = (bd[j] > 1.0f) ? NCLASSES : cls;
        votes[j] = cls;
    }

    int best_cnt = 0, best_cls = 1;
#pragma unroll
    for (int j = 0; j < KNN; ++j) {
        int v = votes[j];
        if (v >= 1 && v <= NCLASSES - 1) {
            int cnt = 0;
#pragma unroll
            for (int i = 0; i < KNN; ++i) cnt += (votes[i] == v) ? 1 : 0;
            if (cnt > best_cnt || (cnt == best_cnt && v < best_cls)) {
                best_cnt = cnt;
                best_cls = v;
            }
        }
    }
    out[oidx] = best_cls;
}

__device__ __forceinline__ int swizzle_block(int b, int nb) {
    if ((nb & 7) == 0) {
        int per = nb >> 3;
        return (b & 7) * per + (b >> 3);
    }
    return b;
}

__global__ __launch_bounds__(256) void bev_knn_aos_kernel(
    const float* __restrict__ pr, const int* __restrict__ pa,
    const uint4* __restrict__ payload, int* __restrict__ out, int P)
{
    int lb = swizzle_block(blockIdx.x, gridDim.x);
    int p = lb * blockDim.x + threadIdx.x;
    if (p >= P) return;
    uint4 w = payload[p];
    float u = __uint_as_float(w.x);
    int x = (int)(w.y & 0x7FFu);
    int y = (int)((w.y >> 11) & 0x7Fu);
    int z = (int)((w.y >> 18) & 0x1Fu);
    bev_knn_body(pr, pa, u, x, y, z, (int)w.z, out);
}

__global__ __launch_bounds__(256) void bev_knn_direct_kernel(
    const float* __restrict__ pr, const int* __restrict__ pa,
    const float* __restrict__ ur, const int* __restrict__ px,
    const int* __restrict__ py, const int* __restrict__ pz,
    int* __restrict__ out, int P)
{
    int p = blockIdx.x * blockDim.x + threadIdx.x;
    if (p >= P) return;
    bev_knn_body(pr, pa, ur[p], px[p], py[p], pz[p], p, out);
}

extern "C" void kernel_launch(void* const* d_in, const int* in_sizes, int n_in,
                              void* d_out, int out_size, void* d_ws, size_t ws_size,
                              hipStream_t stream) {
    const float* pr = (const float*)d_in[0];
    const float* ur = (const float*)d_in[1];
    const int*   pa = (const int*)d_in[2];
    const int*   px = (const int*)d_in[3];
    const int*   py = (const int*)d_in[4];
    const int*   pz = (const int*)d_in[5];
    int* out = (int*)d_out;
    int P = in_sizes[1];
    int block = 256;
    int grid = (P + block - 1) / block;
    int gridH = (P + 4095) / 4096;
    int gridB = (P + BIN_PTS - 1) / BIN_PTS;

    size_t h_b   = (size_t)RADIX * 4;                       // 1 KB
    size_t m_b   = (size_t)RADIX * (size_t)gridB * 4;       // ~512 KB
    size_t m_off = (h_b + m_b + 15) & ~(size_t)15;
    size_t pay_b = (size_t)P * 16;
    size_t need_stable = m_off + 2 * pay_b;
    size_t need_radix  = 4096 + 2 * pay_b;

    if (ws_size >= need_stable) {
        char* ws = (char*)d_ws;
        unsigned* h0   = (unsigned*)ws;
        unsigned* M    = (unsigned*)(ws + h_b);
        uint4*    pay1 = (uint4*)(ws + m_off);
        uint4*    pay2 = (uint4*)(ws + m_off + pay_b);

        hipMemsetAsync(h0, 0, h_b, stream);
        hist0_kernel<<<gridH, 256, 0, stream>>>(px, py, h0, P);
        scan256_kernel<<<1, 256, 0, stream>>>(h0);
        bin_pass1_kernel<<<gridB, BIN_THREADS, 0, stream>>>(ur, px, py, pz,
                                                            h0, pay1, P);
        hist_p2_kernel<<<gridB, BIN_THREADS, 0, stream>>>(pay1, M, gridB, P);
        scan_mat_kernel<<<1, 1024, 0, stream>>>(M, RADIX * gridB);
        bin_pass2_stable_kernel<<<gridB, BIN_THREADS, 0, stream>>>(
            pay1, M, pay2, gridB, P);
        bev_knn_aos_kernel<<<grid, block, 0, stream>>>(pr, pa, pay2, out, P);
    } else if (ws_size >= need_radix) {
        char* ws = (char*)d_ws;
        unsigned* h0   = (unsigned*)ws;
        unsigned* h1   = (unsigned*)(ws + 1024);
        uint4*    pay1 = (uint4*)(ws + 4096);
        uint4*    pay2 = (uint4*)(ws + 4096 + pay_b);

        hipMemsetAsync(ws, 0, 4096, stream);
        hist0_kernel<<<gridH, 256, 0, stream>>>(px, py, h0, P);
        hist1_kernel<<<gridH, 256, 0, stream>>>(py, pz, h1, P);
        scan256_kernel<<<1, 256, 0, stream>>>(h0);
        scan256_kernel<<<1, 256, 0, stream>>>(h1);
        bin_pass1_kernel<<<gridB, BIN_THREADS, 0, stream>>>(ur, px, py, pz,
                                                            h0, pay1, P);
        bin_pass2_kernel<<<gridB, BIN_THREADS, 0, stream>>>(pay1, h1, pay2, P);
        bev_knn_aos_kernel<<<grid, block, 0, stream>>>(pr, pa, pay2, out, P);
    } else {
        bev_knn_direct_kernel<<<grid, block, 0, stream>>>(pr, pa, ur, px, py,
                                                          pz, out, P);
    }
}

// Round 7
// 203.060 us; speedup vs baseline: 1.9683x; 1.9683x over previous
//
#include <hip/hip_runtime.h>
#include <hip/hip_bf16.h>
#include <math.h>

#define KNN 5
#define K3 27
#define CENTER 13
#define NCLASSES 21
#define DIM_D 32
#define DIM_H 128
#define DIM_W 2048

// full sort key (16 bits, z-major): z<<11 | y<<4 | x>>7
// LSD radix: digit0 = key & 0xFF (y-low:4, x>>7:4), digit1 = key >> 8 (z:5, y-high:3)
// payload w.y = x | y<<11 | z<<18 -> d0 = (w.y>>7)&0xFF, d1 = (w.y>>15)&0xFF
#define RADIX 256
#define BIN_PTS 2048
#define BIN_THREADS 256

__device__ __forceinline__ unsigned key16(int x, int y, int z) {
    return ((unsigned)z << 11) | ((unsigned)y << 4) | ((unsigned)x >> 7);
}

// ---------------- pass 0: global digit-0 histogram ----------------
__global__ __launch_bounds__(256) void hist0_kernel(
    const int* __restrict__ px, const int* __restrict__ py,
    unsigned* __restrict__ h0, int P)
{
    __shared__ unsigned lh0[RADIX];
    int t = threadIdx.x;
    lh0[t] = 0;
    __syncthreads();
    int base4 = blockIdx.x * 1024 + t;
#pragma unroll
    for (int g = 0; g < 4; ++g) {
        int i4 = base4 + g * 256;
        int i0 = i4 * 4;
        if (i0 + 3 < P) {
            int4 X = ((const int4*)px)[i4];
            int4 Y = ((const int4*)py)[i4];
            atomicAdd(&lh0[(((unsigned)Y.x & 0xF) << 4) | ((unsigned)X.x >> 7)], 1u);
            atomicAdd(&lh0[(((unsigned)Y.y & 0xF) << 4) | ((unsigned)X.y >> 7)], 1u);
            atomicAdd(&lh0[(((unsigned)Y.z & 0xF) << 4) | ((unsigned)X.z >> 7)], 1u);
            atomicAdd(&lh0[(((unsigned)Y.w & 0xF) << 4) | ((unsigned)X.w >> 7)], 1u);
        } else {
            for (int i = i0; i < P; ++i)
                atomicAdd(&lh0[(((unsigned)py[i] & 0xF) << 4) | ((unsigned)px[i] >> 7)], 1u);
        }
    }
    __syncthreads();
    if (lh0[t]) atomicAdd(&h0[t], lh0[t]);
}

// exclusive scan of one 256-entry array in place
__global__ __launch_bounds__(256) void scan256_kernel(unsigned* __restrict__ h)
{
    __shared__ unsigned ws[4];
    int t = threadIdx.x, lane = t & 63, wid = t >> 6;
    unsigned a = h[t], ia = a;
#pragma unroll
    for (int off = 1; off < 64; off <<= 1) {
        unsigned v = __shfl_up(ia, off);
        if (lane >= off) ia += v;
    }
    if (lane == 63) ws[wid] = ia;
    __syncthreads();
    unsigned b = 0;
#pragma unroll
    for (int w = 0; w < 4; ++w) b += (w < wid) ? ws[w] : 0u;
    h[t] = b + ia - a;
}

// ---------------- binning machinery ----------------
struct BinShared {
    unsigned lh[RADIX];
    unsigned lscan[RADIX];
    unsigned gbase[RADIX];
    unsigned wsum[4];
    uint4 stage[BIN_PTS];   // 32 KB
};

__device__ __forceinline__ void bin_local_scan(BinShared& S, int t)
{
    int lane = t & 63, wid = t >> 6;
    unsigned c = S.lh[t];
    unsigned inc = c;
#pragma unroll
    for (int off = 1; off < 64; off <<= 1) {
        unsigned v = __shfl_up(inc, off);
        if (lane >= off) inc += v;
    }
    if (lane == 63) S.wsum[wid] = inc;
    __syncthreads();
    unsigned wb = 0;
#pragma unroll
    for (int w = 0; w < 4; ++w) wb += (w < wid) ? S.wsum[w] : 0u;
    S.lscan[t] = wb + inc - c;
}

// pass 1: read original SoA arrays, bin by digit0 (cursor atomics on h0;
// grouping by d0 is exact, intra-d0 order is don't-care for pass 2)
__global__ __launch_bounds__(BIN_THREADS) void bin_pass1_kernel(
    const float* __restrict__ ur, const int* __restrict__ px,
    const int* __restrict__ py, const int* __restrict__ pz,
    unsigned* __restrict__ g0, uint4* __restrict__ outp, int P)
{
    __shared__ BinShared S;
    int t = threadIdx.x;
    int bstart = blockIdx.x * BIN_PTS;
    int n = min(BIN_PTS, P - bstart);
    S.lh[t] = 0;
    __syncthreads();

    uint4 pay[8];
    unsigned rk[8], dg[8];
#pragma unroll
    for (int g = 0; g < 2; ++g) {
        int i4 = (bstart >> 2) + g * 256 + t;
        int i0 = i4 * 4;
        if (i0 + 3 < P) {
            int4 X = ((const int4*)px)[i4];
            int4 Y = ((const int4*)py)[i4];
            int4 Z = ((const int4*)pz)[i4];
            float4 U = ((const float4*)ur)[i4];
            int xs[4] = {X.x, X.y, X.z, X.w};
            int ys[4] = {Y.x, Y.y, Y.z, Y.w};
            int zs[4] = {Z.x, Z.y, Z.z, Z.w};
            float us[4] = {U.x, U.y, U.z, U.w};
#pragma unroll
            for (int c = 0; c < 4; ++c) {
                int j = g * 4 + c;
                unsigned k = key16(xs[c], ys[c], zs[c]);
                dg[j] = k & 0xFFu;
                rk[j] = atomicAdd(&S.lh[dg[j]], 1u);
                pay[j] = make_uint4(__float_as_uint(us[c]),
                    (unsigned)xs[c] | ((unsigned)ys[c] << 11) | ((unsigned)zs[c] << 18),
                    (unsigned)(i0 + c), 0u);
            }
        } else {
#pragma unroll
            for (int c = 0; c < 4; ++c) {
                int j = g * 4 + c;
                int gi = i0 + c;
                if (gi < P) {
                    int x = px[gi], y = py[gi], z = pz[gi];
                    unsigned k = key16(x, y, z);
                    dg[j] = k & 0xFFu;
                    rk[j] = atomicAdd(&S.lh[dg[j]], 1u);
                    pay[j] = make_uint4(__float_as_uint(ur[gi]),
                        (unsigned)x | ((unsigned)y << 11) | ((unsigned)z << 18),
                        (unsigned)gi, 0u);
                } else {
                    dg[j] = 0xFFFFFFFFu;
                }
            }
        }
    }
    __syncthreads();
    bin_local_scan(S, t);
    S.gbase[t] = S.lh[t] ? atomicAdd(&g0[t], S.lh[t]) : 0u;
    __syncthreads();
#pragma unroll
    for (int j = 0; j < 8; ++j)
        if (dg[j] != 0xFFFFFFFFu)
            S.stage[S.lscan[dg[j]] + rk[j]] = pay[j];
    __syncthreads();
#pragma unroll
    for (int j = 0; j < 8; ++j) {
        int s = j * 256 + t;
        if (s < n) {
            uint4 v = S.stage[s];
            unsigned d = (v.y >> 7) & 0xFFu;
            unsigned pos = S.gbase[d] + ((unsigned)s - S.lscan[d]);
            outp[pos] = v;
        }
    }
}

// per-pass-2-block digit-1 histogram -> M[d1 * gridB + block] (digit-major)
__global__ __launch_bounds__(BIN_THREADS) void hist_p2_kernel(
    const uint4* __restrict__ inp, unsigned* __restrict__ M,
    int gridB, int P)
{
    __shared__ unsigned lh[RADIX];
    int t = threadIdx.x;
    lh[t] = 0;
    __syncthreads();
    int bstart = blockIdx.x * BIN_PTS;
#pragma unroll
    for (int j = 0; j < 8; ++j) {
        int i = bstart + j * 256 + t;
        if (i < P) {
            uint4 v = inp[i];
            atomicAdd(&lh[(v.y >> 15) & 0xFFu], 1u);
        }
    }
    __syncthreads();
    M[(unsigned)t * (unsigned)gridB + blockIdx.x] = lh[t];
}

// per-digit exclusive scan: block d scans row M[d][0..gridB), total -> T[d].
// 256 independent workgroups (vs R5's single-block 131K-entry serial scan).
__global__ __launch_bounds__(1024) void scan_digit_kernel(
    unsigned* __restrict__ M, unsigned* __restrict__ T, int gridB)
{
    __shared__ unsigned wsum[16];
    unsigned* row = M + (size_t)blockIdx.x * (unsigned)gridB;
    int t = threadIdx.x, lane = t & 63, wid = t >> 6;
    int C = (gridB + 1023) / 1024;
    int lo = t * C, hi = min(lo + C, gridB);

    unsigned s = 0;
    for (int i = lo; i < hi; ++i) s += row[i];
    unsigned incl = s;
#pragma unroll
    for (int off = 1; off < 64; off <<= 1) {
        unsigned v = __shfl_up(incl, off);
        if (lane >= off) incl += v;
    }
    if (lane == 63) wsum[wid] = incl;
    __syncthreads();
    if (wid == 0 && lane < 16) {
        unsigned v = wsum[lane], iv = v;
#pragma unroll
        for (int off = 1; off < 16; off <<= 1) {
            unsigned u = __shfl_up(iv, off);
            if (lane >= off) iv += u;
        }
        wsum[lane] = iv - v;
    }
    __syncthreads();
    unsigned run = wsum[wid] + (incl - s);
    for (int i = lo; i < hi; ++i) {
        unsigned v = row[i];
        row[i] = run;
        run += v;
    }
    if (t == 1023) T[blockIdx.x] = run;   // block total (thread 1023's run end)
}

// pass 2 STABLE: deterministic base = T[d] (scanned) + M[d][block].
__global__ __launch_bounds__(BIN_THREADS) void bin_pass2_stable_kernel(
    const uint4* __restrict__ inp, const unsigned* __restrict__ M,
    const unsigned* __restrict__ T, uint4* __restrict__ outp,
    int gridB, int P)
{
    __shared__ BinShared S;
    int t = threadIdx.x;
    int bstart = blockIdx.x * BIN_PTS;
    int n = min(BIN_PTS, P - bstart);
    S.lh[t] = 0;
    __syncthreads();

    uint4 pay[8];
    unsigned rk[8], dg[8];
#pragma unroll
    for (int j = 0; j < 8; ++j) {
        int i = bstart + j * 256 + t;
        if (i < P) {
            uint4 v = inp[i];
            pay[j] = v;
            dg[j] = (v.y >> 15) & 0xFFu;
            rk[j] = atomicAdd(&S.lh[dg[j]], 1u);
        } else {
            dg[j] = 0xFFFFFFFFu;
        }
    }
    __syncthreads();
    bin_local_scan(S, t);
    S.gbase[t] = T[t] + M[(unsigned)t * (unsigned)gridB + blockIdx.x];
    __syncthreads();
#pragma unroll
    for (int j = 0; j < 8; ++j)
        if (dg[j] != 0xFFFFFFFFu)
            S.stage[S.lscan[dg[j]] + rk[j]] = pay[j];
    __syncthreads();
#pragma unroll
    for (int j = 0; j < 8; ++j) {
        int s = j * 256 + t;
        if (s < n) {
            uint4 v = S.stage[s];
            unsigned d = (v.y >> 15) & 0xFFu;
            unsigned pos = S.gbase[d] + ((unsigned)s - S.lscan[d]);
            outp[pos] = v;
        }
    }
}

// ---------------- KNN main kernel (R1-verified body) ----------------
__device__ __forceinline__ void bev_knn_body(
    const float* __restrict__ pr, const int* __restrict__ pa,
    float u, int x, int y, int z, int oidx, int* __restrict__ out)
{
    float dist[K3];
#pragma unroll
    for (int k = 0; k < K3; ++k) {
        const int dz = k / 9 - 1;
        const int dy = (k / 3) % 3 - 1;
        const int dx = k % 3 - 1;
        int zz = z + dz, yy = y + dy, xx = x + dx;
        bool ok = ((unsigned)zz < (unsigned)DIM_D) &
                  ((unsigned)yy < (unsigned)DIM_H) &
                  ((unsigned)xx < (unsigned)DIM_W);
        int zi = ok ? zz : 0;
        int yi = ok ? yy : 0;
        int xi = ok ? xx : 0;
        float r = pr[((size_t)zi * DIM_H + yi) * DIM_W + xi];
        r = ok ? r : 0.0f;
        r = (r < 0.0f) ? INFINITY : r;
        float d = fabsf(r - u);
        dist[k] = (k == CENTER) ? 0.0f : d;
    }

    float bd[KNN];
    int   bk[KNN];
#pragma unroll
    for (int j = 0; j < KNN; ++j) { bd[j] = INFINITY; bk[j] = -1; }
#pragma unroll
    for (int k = 0; k < K3; ++k) {
        float dcur = dist[k];
        int   kcur = k;
#pragma unroll
        for (int j = 0; j < KNN; ++j) {
            bool take = dcur < bd[j];
            float td = bd[j]; int tk = bk[j];
            bd[j] = take ? dcur : bd[j];
            bk[j] = take ? kcur : bk[j];
            dcur  = take ? td : dcur;
            kcur  = take ? tk : kcur;
        }
    }

    int votes[KNN];
#pragma unroll
    for (int j = 0; j < KNN; ++j) {
        int k = bk[j];
        const int dz = k / 9 - 1;
        const int dy = (k / 3) % 3 - 1;
        const int dx = k % 3 - 1;
        int zz = z + dz, yy = y + dy, xx = x + dx;
        bool ok = ((unsigned)zz < (unsigned)DIM_D) &
                  ((unsigned)yy < (unsigned)DIM_H) &
                  ((unsigned)xx < (unsigned)DIM_W);
        int zi = ok ? zz : 0;
        int yi = ok ? yy : 0;
        int xi = ok ? xx : 0;
        int cls = pa[((size_t)zi * DIM_H + yi) * DIM_W + xi];
        cls = ok ? cls : 0;
        cls = (bd[j] > 1.0f) ? NCLASSES : cls;
        votes[j] = cls;
    }

    int best_cnt = 0, best_cls = 1;
#pragma unroll
    for (int j = 0; j < KNN; ++j) {
        int v = votes[j];
        if (v >= 1 && v <= NCLASSES - 1) {
            int cnt = 0;
#pragma unroll
            for (int i = 0; i < KNN; ++i) cnt += (votes[i] == v) ? 1 : 0;
            if (cnt > best_cnt || (cnt == best_cnt && v < best_cls)) {
                best_cnt = cnt;
                best_cls = v;
            }
        }
    }
    out[oidx] = best_cls;
}

__device__ __forceinline__ int swizzle_block(int b, int nb) {
    if ((nb & 7) == 0) {
        int per = nb >> 3;
        return (b & 7) * per + (b >> 3);
    }
    return b;
}

__global__ __launch_bounds__(256) void bev_knn_aos_kernel(
    const float* __restrict__ pr, const int* __restrict__ pa,
    const uint4* __restrict__ payload, int* __restrict__ out, int P)
{
    int lb = swizzle_block(blockIdx.x, gridDim.x);
    int p = lb * blockDim.x + threadIdx.x;
    if (p >= P) return;
    uint4 w = payload[p];
    float u = __uint_as_float(w.x);
    int x = (int)(w.y & 0x7FFu);
    int y = (int)((w.y >> 11) & 0x7Fu);
    int z = (int)((w.y >> 18) & 0x1Fu);
    bev_knn_body(pr, pa, u, x, y, z, (int)w.z, out);
}

__global__ __launch_bounds__(256) void bev_knn_direct_kernel(
    const float* __restrict__ pr, const int* __restrict__ pa,
    const float* __restrict__ ur, const int* __restrict__ px,
    const int* __restrict__ py, const int* __restrict__ pz,
    int* __restrict__ out, int P)
{
    int p = blockIdx.x * blockDim.x + threadIdx.x;
    if (p >= P) return;
    bev_knn_body(pr, pa, ur[p], px[p], py[p], pz[p], p, out);
}

extern "C" void kernel_launch(void* const* d_in, const int* in_sizes, int n_in,
                              void* d_out, int out_size, void* d_ws, size_t ws_size,
                              hipStream_t stream) {
    const float* pr = (const float*)d_in[0];
    const float* ur = (const float*)d_in[1];
    const int*   pa = (const int*)d_in[2];
    const int*   px = (const int*)d_in[3];
    const int*   py = (const int*)d_in[4];
    const int*   pz = (const int*)d_in[5];
    int* out = (int*)d_out;
    int P = in_sizes[1];
    int block = 256;
    int grid = (P + block - 1) / block;
    int gridH = (P + 4095) / 4096;
    int gridB = (P + BIN_PTS - 1) / BIN_PTS;

    size_t h_b   = (size_t)RADIX * 4;                       // 1 KB
    size_t t_b   = (size_t)RADIX * 4;                       // 1 KB
    size_t m_b   = (size_t)RADIX * (size_t)gridB * 4;       // ~512 KB
    size_t m_off = (h_b + t_b + m_b + 15) & ~(size_t)15;
    size_t pay_b = (size_t)P * 16;
    size_t need_stable = m_off + 2 * pay_b;

    if (ws_size >= need_stable) {
        char* ws = (char*)d_ws;
        unsigned* h0   = (unsigned*)ws;
        unsigned* T    = (unsigned*)(ws + h_b);
        unsigned* M    = (unsigned*)(ws + h_b + t_b);
        uint4*    pay1 = (uint4*)(ws + m_off);
        uint4*    pay2 = (uint4*)(ws + m_off + pay_b);

        hipMemsetAsync(h0, 0, h_b, stream);
        hist0_kernel<<<gridH, 256, 0, stream>>>(px, py, h0, P);
        scan256_kernel<<<1, 256, 0, stream>>>(h0);
        bin_pass1_kernel<<<gridB, BIN_THREADS, 0, stream>>>(ur, px, py, pz,
                                                            h0, pay1, P);
        hist_p2_kernel<<<gridB, BIN_THREADS, 0, stream>>>(pay1, M, gridB, P);
        scan_digit_kernel<<<RADIX, 1024, 0, stream>>>(M, T, gridB);
        scan256_kernel<<<1, 256, 0, stream>>>(T);
        bin_pass2_stable_kernel<<<gridB, BIN_THREADS, 0, stream>>>(
            pay1, M, T, pay2, gridB, P);
        bev_knn_aos_kernel<<<grid, block, 0, stream>>>(pr, pa, pay2, out, P);
    } else {
        bev_knn_direct_kernel<<<grid, block, 0, stream>>>(pr, pa, ur, px, py,
                                                          pz, out, P);
    }
}